// Round 2
// baseline (258.705 us; speedup 1.0000x reference)
//
#include <hip/hip_runtime.h>
#include <math.h>

// Problem constants
#define CH   64
#define FD   128
#define HS   64
#define FS   128
#define NB   8
#define NCTX 3

// workspace layout (float offsets) — only A-frags + bq used
#define WS_BQ   4227072                 // bq[64]
#define WS_AVH  4227136                 // conv A frags hi: [2][72][64][8] shorts
#define WS_AQH  4264000                 // qt A frags hi  : [2][8][64][8] shorts
#define WS_AQL  4268096
#define WS_AKH  4272192                 // key A frags
#define WS_AKL  4276288

typedef short  s16x8  __attribute__((ext_vector_type(8)));
typedef float  f32x16 __attribute__((ext_vector_type(16)));

__device__ inline unsigned short bf16_rne(float x) {
  unsigned u = __float_as_uint(x);
  u += 0x7FFFu + ((u >> 16) & 1u);
  return (unsigned short)(u >> 16);
}
__device__ inline void split2(float x, unsigned short& h, unsigned short& l) {
  h = bf16_rne(x);
  l = bf16_rne(x - __uint_as_float((unsigned)h << 16));
}

// ---------------------------------------------------------------------------
// afrag_prep: MFMA A-fragments (conv hi; qt/key hi+lo) + bq. 45 blocks.
// (unchanged)
// ---------------------------------------------------------------------------
__global__ __launch_bounds__(256) void afrag_prep(
    const float* __restrict__ Wc, const float* __restrict__ Wf,
    const float* __restrict__ bf, const float* __restrict__ Wk,
    const float* __restrict__ Vw, float* __restrict__ ws) {
  int id = blockIdx.x * 256 + threadIdx.x;
  unsigned short* avh = (unsigned short*)(ws + WS_AVH);
  unsigned short* aqh = (unsigned short*)(ws + WS_AQH);
  unsigned short* aql = (unsigned short*)(ws + WS_AQL);
  unsigned short* akh = (unsigned short*)(ws + WS_AKH);
  unsigned short* akl = (unsigned short*)(ws + WS_AKL);

  if (id < 9216) {                       // conv frags: hi only
    int tile = id / 4608, rem = id % 4608;
    int q = rem >> 6, l = rem & 63;
    int am = l & 31, kh = l >> 5;
    int c = tile * 32 + am, tap = q >> 3, kf = q & 7;
#pragma unroll
    for (int j = 0; j < 8; ++j) {
      int f = kf * 16 + kh * 8 + j;
      avh[id * 8 + j] = bf16_rne(Vw[(c * FD + f) * 9 + tap]);
    }
  } else if (id < 10240) {               // qt: Wq = Wc^T Wf inline
    int i2 = id - 9216;
    int tile = i2 >> 9, rem = i2 & 511;
    int q = rem >> 6, l = rem & 63;
    int am = l & 31, kh = l >> 5;
    int c = tile * 32 + am;
#pragma unroll
    for (int j = 0; j < 8; ++j) {
      int f = q * 16 + kh * 8 + j;
      float acc = 0.f;
      for (int d = 0; d < CH; ++d)
        acc = fmaf(Wc[d * CH + c], Wf[d * FD + f], acc);
      unsigned short h, lo; split2(acc, h, lo);
      aqh[i2 * 8 + j] = h; aql[i2 * 8 + j] = lo;
    }
  } else if (id < 11264) {               // keys: Wk direct
    int i3 = id - 10240;
    int tile = i3 >> 9, rem = i3 & 511;
    int q = rem >> 6, l = rem & 63;
    int am = l & 31, kh = l >> 5;
    int c = tile * 32 + am;
#pragma unroll
    for (int j = 0; j < 8; ++j) {
      int f = q * 16 + kh * 8 + j;
      unsigned short h, lo; split2(Wk[c * FD + f], h, lo);
      akh[i3 * 8 + j] = h; akl[i3 * 8 + j] = lo;
    }
  } else if (id < 11328) {               // bq = Wc^T bf
    int c = id - 11264;
    float acc = 0.f;
    for (int d = 0; d < CH; ++d) acc = fmaf(Wc[d * CH + c], bf[d], acc);
    ws[WS_BQ + c] = acc;
  }
}

// ---------------------------------------------------------------------------
// fused_kernel v2: one block per (b, y, xh). 1024 blocks x 256 threads
// (4 blocks/CU vs 2 before -> cross-block phase overlap hides latency).
// Waves: 0,1 = conv ct0/ct1; 2,3 = qt+keys ct0/ct1. Each block covers a
// 32-px half of the half-res row y and the matching 64-px half of output
// rows 2y, 2y+1. Halo (34 cols) staged per block; borders via predication.
// ---------------------------------------------------------------------------
__global__ __launch_bounds__(256) void fused_kernel(
    const float* __restrict__ m, const float* __restrict__ Vb,
    const float* __restrict__ bk, const float* __restrict__ ctx,
    float* __restrict__ out, const float* __restrict__ ws) {
  const int b  = blockIdx.x >> 7;
  const int y  = (blockIdx.x >> 1) & 63;
  const int xh = blockIdx.x & 1;
  const int t = threadIdx.x, lane = t & 63;
  const int wave = __builtin_amdgcn_readfirstlane(t >> 6);
  const int am = lane & 31, kh = lane >> 5;

  // HI (26112 B) overlaid with phase-B buffers (20992 B); HI dead after B2.
  __shared__ __align__(16) union {
    short HI[3][8][34][2][8];            // [row][kf][halo col][kh][8f]
    struct {
      float  QT[CH][34];                 // [c][hx] row y half, with bq
      float  VAL[CH][34];                // [c][hx] row y half, with Vb
      float4 wpart[4][3][16];            // [wave][n][quad]
      float  l3red[2][64];               // [ct][kh*32+px] qk partials
    } p;
  } U;

  // ---- stage hi: 48 tasks (row,kf,khh), 12/wave; lanes 0..33 = halo cols ----
  const int gx0 = 32 * xh - 1;
#pragma unroll
  for (int i = 0; i < 12; ++i) {
    const int tk = wave * 12 + i;              // 0..47
    const int row = tk >> 4, kf = (tk >> 1) & 7, khh = tk & 1;
    const int yy = y + row - 1;
    const int gx = gx0 + lane;
    if (lane < 34) {
      s16x8 hi;
      if (yy >= 0 && yy < HS && gx >= 0 && gx < HS) {
#pragma unroll
        for (int j = 0; j < 8; ++j) {
          const int f = kf * 16 + khh * 8 + j;
          hi[j] = (short)bf16_rne(m[((b * FD + f) * HS + yy) * HS + gx]);
        }
      } else {
#pragma unroll
        for (int j = 0; j < 8; ++j) hi[j] = 0;
      }
      *(s16x8*)&U.HI[row][kf][lane][khh][0] = hi;
    }
  }
  __syncthreads();                             // B1: HI staged

  const int ct = wave & 1;
  f32x16 acc, q1, q2, k1, k2;
  float l3part = 0.f;

  if (wave < 2) {
    // ---- conv: 32c x 32px tile, all 72 K-chunks, A-hi x B-hi ----
    const unsigned short* avh = (const unsigned short*)(ws + WS_AVH);
#pragma unroll
    for (int i = 0; i < 16; ++i) acc[i] = 0.f;
#pragma unroll 8
    for (int q = 0; q < 72; ++q) {
      const int tap = q >> 3, kf = q & 7;
      const s16x8 ah = *(const s16x8*)(avh + ((ct * 72 + q) * 64 + lane) * 8);
      const s16x8 bh = *(const s16x8*)&U.HI[tap / 3][kf][am + tap % 3][kh][0];
      acc = __builtin_amdgcn_mfma_f32_32x32x16_bf16(ah, bh, acc, 0, 0, 0);
    }
  } else {
    // ---- qt + keys: K=128, 3-MFMA hi/lo split each ----
    const unsigned short* aqh = (const unsigned short*)(ws + WS_AQH);
    const unsigned short* aql = (const unsigned short*)(ws + WS_AQL);
    const unsigned short* akh = (const unsigned short*)(ws + WS_AKH);
    const unsigned short* akl = (const unsigned short*)(ws + WS_AKL);
#pragma unroll
    for (int i = 0; i < 16; ++i) { q1[i] = 0.f; q2[i] = 0.f; k1[i] = 0.f; k2[i] = 0.f; }
#pragma unroll
    for (int q = 0; q < 8; ++q) {
      const s16x8 bh = *(const s16x8*)&U.HI[1][q][am + 1][kh][0];
      s16x8 bl;
#pragma unroll
      for (int j = 0; j < 8; ++j) {
        const float mv = m[((b * FD + q * 16 + kh * 8 + j) * HS + y) * HS + 32 * xh + am];
        const float hf = __uint_as_float(((unsigned)(unsigned short)bh[j]) << 16);
        bl[j] = (short)bf16_rne(mv - hf);
      }
      const s16x8 ah = *(const s16x8*)(aqh + ((ct * 8 + q) * 64 + lane) * 8);
      const s16x8 al = *(const s16x8*)(aql + ((ct * 8 + q) * 64 + lane) * 8);
      const s16x8 kah = *(const s16x8*)(akh + ((ct * 8 + q) * 64 + lane) * 8);
      const s16x8 kal = *(const s16x8*)(akl + ((ct * 8 + q) * 64 + lane) * 8);
      q1 = __builtin_amdgcn_mfma_f32_32x32x16_bf16(ah, bh, q1, 0, 0, 0);
      q1 = __builtin_amdgcn_mfma_f32_32x32x16_bf16(al, bh, q1, 0, 0, 0);
      q2 = __builtin_amdgcn_mfma_f32_32x32x16_bf16(ah, bl, q2, 0, 0, 0);
      k1 = __builtin_amdgcn_mfma_f32_32x32x16_bf16(kah, bh, k1, 0, 0, 0);
      k1 = __builtin_amdgcn_mfma_f32_32x32x16_bf16(kal, bh, k1, 0, 0, 0);
      k2 = __builtin_amdgcn_mfma_f32_32x32x16_bf16(kah, bl, k2, 0, 0, 0);
    }
  }
  __syncthreads();                             // B2: HI dead, union reusable

  // ---- spill accumulators to LDS ----
  if (wave < 2) {
#pragma unroll
    for (int r = 0; r < 16; ++r) {
      const int c = ct * 32 + (r & 3) + 8 * (r >> 2) + 4 * kh;
      U.p.VAL[c][am] = acc[r] + Vb[c];
    }
  } else {
#pragma unroll
    for (int r = 0; r < 16; ++r) {
      const int c = ct * 32 + (r & 3) + 8 * (r >> 2) + 4 * kh;
      const float qvv = q1[r] + q2[r] + ws[WS_BQ + c];
      const float kvv = k1[r] + k2[r] + bk[c];
      U.p.QT[c][am] = qvv;
      l3part = fmaf(qvv, kvv, l3part);
    }
    U.p.l3red[ct][lane] = l3part;
  }
  __syncthreads();                             // B3: QT/VAL/l3red ready

  // =======================================================================
  // Phase B: output rows 2y, 2y+1, x in [64*xh, 64*xh+64)
  // =======================================================================
  const int quad = t & 15;
  const int cg   = t >> 4;
  const int c0   = cg * 4;
  const int x    = 64 * xh + quad * 4;
  const int hx   = quad * 2;                   // half-res px within block
  const int cs = FS * FS, ns = CH * FS * FS;

  // l3 logits for this thread's two half-res pixels (sum ct x kh partials)
  const float l3a = U.p.l3red[0][hx]     + U.p.l3red[0][hx + 32]
                  + U.p.l3red[1][hx]     + U.p.l3red[1][hx + 32];
  const float l3b = U.p.l3red[0][hx + 1] + U.p.l3red[0][hx + 33]
                  + U.p.l3red[1][hx + 1] + U.p.l3red[1][hx + 33];

  // u-invariant LDS reads hoisted
  float2 qv[4], vv[4];
#pragma unroll
  for (int j = 0; j < 4; ++j) {
    qv[j] = *(const float2*)&U.p.QT[c0 + j][hx];
    vv[j] = *(const float2*)&U.p.VAL[c0 + j][hx];
  }

#pragma unroll 1
  for (int u = 0; u < 2; ++u) {
    const int hrow = 2 * y + u;
    const float* cb = ctx + (size_t)(b * NCTX * CH) * cs + (size_t)hrow * FS + x;
    float* op = out + (size_t)(b * CH) * cs + (size_t)hrow * FS + x;

    float4 cv[3][4];
#pragma unroll
    for (int j = 0; j < 4; ++j) {
      const int c = c0 + j;
      cv[0][j] = *(const float4*)(cb + c * cs);
      cv[1][j] = *(const float4*)(cb + ns + c * cs);
      cv[2][j] = *(const float4*)(cb + 2 * ns + c * cs);
    }

    float4 pl[3];
#pragma unroll
    for (int n = 0; n < 3; ++n) {
      pl[n].x = pl[n].y = pl[n].z = pl[n].w = 0.f;
#pragma unroll
      for (int j = 0; j < 4; ++j) {
        pl[n].x = fmaf(cv[n][j].x, qv[j].x, pl[n].x);
        pl[n].y = fmaf(cv[n][j].y, qv[j].x, pl[n].y);
        pl[n].z = fmaf(cv[n][j].z, qv[j].y, pl[n].z);
        pl[n].w = fmaf(cv[n][j].w, qv[j].y, pl[n].w);
      }
    }

    // in-wave reduce over the wave's 4 c-groups (lanes ^16, ^32)
#pragma unroll
    for (int n = 0; n < 3; ++n) {
      pl[n].x += __shfl_xor(pl[n].x, 16, 64);
      pl[n].y += __shfl_xor(pl[n].y, 16, 64);
      pl[n].z += __shfl_xor(pl[n].z, 16, 64);
      pl[n].w += __shfl_xor(pl[n].w, 16, 64);
      pl[n].x += __shfl_xor(pl[n].x, 32, 64);
      pl[n].y += __shfl_xor(pl[n].y, 32, 64);
      pl[n].z += __shfl_xor(pl[n].z, 32, 64);
      pl[n].w += __shfl_xor(pl[n].w, 32, 64);
    }
    __syncthreads();                           // wpart free
    if ((lane >> 4) == 0) {
#pragma unroll
      for (int n = 0; n < 3; ++n) U.p.wpart[wave][n][quad] = pl[n];
    }
    __syncthreads();                           // wpart ready

    float4 L[3];
#pragma unroll
    for (int n = 0; n < 3; ++n) {
      const float4 p0 = U.p.wpart[0][n][quad];
      const float4 p1 = U.p.wpart[1][n][quad];
      const float4 p2 = U.p.wpart[2][n][quad];
      const float4 p3 = U.p.wpart[3][n][quad];
      L[n].x = (p0.x + p1.x) + (p2.x + p3.x);
      L[n].y = (p0.y + p1.y) + (p2.y + p3.y);
      L[n].z = (p0.z + p1.z) + (p2.z + p3.z);
      L[n].w = (p0.w + p1.w) + (p2.w + p3.w);
    }

    float A0[4], A1[4], A2[4], A3[4];
    const float* L0p = (const float*)&L[0];
    const float* L1p = (const float*)&L[1];
    const float* L2p = (const float*)&L[2];
#pragma unroll
    for (int k = 0; k < 4; ++k) {
      float L0 = L0p[k], L1 = L1p[k], L2 = L2p[k];
      float L3 = (k < 2) ? l3a : l3b;
      float mx = fmaxf(fmaxf(L0, L1), fmaxf(L2, L3));
      float e0 = __expf(L0 - mx), e1 = __expf(L1 - mx);
      float e2 = __expf(L2 - mx), e3 = __expf(L3 - mx);
      float inv = 1.f / (e0 + e1 + e2 + e3);
      A0[k] = e0 * inv; A1[k] = e1 * inv; A2[k] = e2 * inv; A3[k] = e3 * inv;
    }

#pragma unroll
    for (int j = 0; j < 4; ++j) {
      const int c = c0 + j;
      float4 o;
      o.x = fmaf(A0[0], cv[0][j].x, fmaf(A1[0], cv[1][j].x, fmaf(A2[0], cv[2][j].x, A3[0] * vv[j].x)));
      o.y = fmaf(A0[1], cv[0][j].y, fmaf(A1[1], cv[1][j].y, fmaf(A2[1], cv[2][j].y, A3[1] * vv[j].x)));
      o.z = fmaf(A0[2], cv[0][j].z, fmaf(A1[2], cv[1][j].z, fmaf(A2[2], cv[2][j].z, A3[2] * vv[j].y)));
      o.w = fmaf(A0[3], cv[0][j].w, fmaf(A1[3], cv[1][j].w, fmaf(A2[3], cv[2][j].w, A3[3] * vv[j].y)));
      *(float4*)(op + c * cs) = o;
    }
  }
}

// ---------------------------------------------------------------------------
extern "C" void kernel_launch(void* const* d_in, const int* in_sizes, int n_in,
                              void* d_out, int out_size, void* d_ws, size_t ws_size,
                              hipStream_t stream) {
  const float* ctx = (const float*)d_in[0];
  const float* ms  = (const float*)d_in[1];
  const float* Wc  = (const float*)d_in[2];
  // d_in[3] = bc : cancels in softmax
  const float* Wf  = (const float*)d_in[4];
  const float* bf  = (const float*)d_in[5];
  const float* Wk  = (const float*)d_in[6];
  const float* bk  = (const float*)d_in[7];
  const float* Vw  = (const float*)d_in[8];
  const float* Vb  = (const float*)d_in[9];
  float* ws  = (float*)d_ws;
  float* out = (float*)d_out;

  afrag_prep<<<45, 256, 0, stream>>>(Wc, Wf, bf, Wk, Vw, ws);
  fused_kernel<<<NB * HS * 2, 256, 0, stream>>>(ms, Vb, bk, ctx, out, ws);
}

// Round 3
// 254.358 us; speedup vs baseline: 1.0171x; 1.0171x over previous
//
#include <hip/hip_runtime.h>
#include <math.h>

// Problem constants
#define CH   64
#define FD   128
#define HS   64
#define FS   128
#define NB   8
#define NCTX 3

// workspace layout (float offsets) — only A-frags + bq used
#define WS_BQ   4227072                 // bq[64]
#define WS_AVH  4227136                 // conv A frags hi: [2][72][64][8] shorts
#define WS_AQH  4264000                 // qt A frags hi  : [2][8][64][8] shorts
#define WS_AQL  4268096
#define WS_AKH  4272192                 // key A frags
#define WS_AKL  4276288

typedef short  s16x8  __attribute__((ext_vector_type(8)));
typedef float  f32x16 __attribute__((ext_vector_type(16)));
typedef __attribute__((address_space(3))) unsigned int lds_u32;
typedef __attribute__((address_space(1))) const unsigned int glob_u32;

__device__ inline unsigned short bf16_rne(float x) {
  unsigned u = __float_as_uint(x);
  u += 0x7FFFu + ((u >> 16) & 1u);
  return (unsigned short)(u >> 16);
}
__device__ inline void split2(float x, unsigned short& h, unsigned short& l) {
  h = bf16_rne(x);
  l = bf16_rne(x - __uint_as_float((unsigned)h << 16));
}

// raw barrier: drain LDS ops only — global loads stay in flight (the point!)
__device__ inline void rbar() {
  asm volatile("s_waitcnt lgkmcnt(0)" ::: "memory");
  __builtin_amdgcn_s_barrier();
  __builtin_amdgcn_sched_barrier(0);
}

// ---------------------------------------------------------------------------
// afrag_prep: MFMA A-fragments (conv hi; qt/key hi+lo) + bq. 45 blocks.
// (unchanged)
// ---------------------------------------------------------------------------
__global__ __launch_bounds__(256) void afrag_prep(
    const float* __restrict__ Wc, const float* __restrict__ Wf,
    const float* __restrict__ bf, const float* __restrict__ Wk,
    const float* __restrict__ Vw, float* __restrict__ ws) {
  int id = blockIdx.x * 256 + threadIdx.x;
  unsigned short* avh = (unsigned short*)(ws + WS_AVH);
  unsigned short* aqh = (unsigned short*)(ws + WS_AQH);
  unsigned short* aql = (unsigned short*)(ws + WS_AQL);
  unsigned short* akh = (unsigned short*)(ws + WS_AKH);
  unsigned short* akl = (unsigned short*)(ws + WS_AKL);

  if (id < 9216) {                       // conv frags: hi only
    int tile = id / 4608, rem = id % 4608;
    int q = rem >> 6, l = rem & 63;
    int am = l & 31, kh = l >> 5;
    int c = tile * 32 + am, tap = q >> 3, kf = q & 7;
#pragma unroll
    for (int j = 0; j < 8; ++j) {
      int f = kf * 16 + kh * 8 + j;
      avh[id * 8 + j] = bf16_rne(Vw[(c * FD + f) * 9 + tap]);
    }
  } else if (id < 10240) {               // qt: Wq = Wc^T Wf inline
    int i2 = id - 9216;
    int tile = i2 >> 9, rem = i2 & 511;
    int q = rem >> 6, l = rem & 63;
    int am = l & 31, kh = l >> 5;
    int c = tile * 32 + am;
#pragma unroll
    for (int j = 0; j < 8; ++j) {
      int f = q * 16 + kh * 8 + j;
      float acc = 0.f;
      for (int d = 0; d < CH; ++d)
        acc = fmaf(Wc[d * CH + c], Wf[d * FD + f], acc);
      unsigned short h, lo; split2(acc, h, lo);
      aqh[i2 * 8 + j] = h; aql[i2 * 8 + j] = lo;
    }
  } else if (id < 11264) {               // keys: Wk direct
    int i3 = id - 10240;
    int tile = i3 >> 9, rem = i3 & 511;
    int q = rem >> 6, l = rem & 63;
    int am = l & 31, kh = l >> 5;
    int c = tile * 32 + am;
#pragma unroll
    for (int j = 0; j < 8; ++j) {
      int f = q * 16 + kh * 8 + j;
      unsigned short h, lo; split2(Wk[c * FD + f], h, lo);
      akh[i3 * 8 + j] = h; akl[i3 * 8 + j] = lo;
    }
  } else if (id < 11328) {               // bq = Wc^T bf
    int c = id - 11264;
    float acc = 0.f;
    for (int d = 0; d < CH; ++d) acc = fmaf(Wc[d * CH + c], bf[d], acc);
    ws[WS_BQ + c] = acc;
  }
}

// issue one 48KB ctx unit (3n x 64c x 64px) into an LDS slot via
// global_load_lds. ONE wave calls this; LDS dest is wave-uniform base,
// HW adds lane*16B. instr i covers rows 4i..4i+3 of [n][c][px] layout.
__device__ inline void issue_unit(const float* __restrict__ ctx, float* slot,
                                  int b, int hrow, int x0, int lane) {
  const int rl = lane >> 4;              // sub-row 0..3
  const int pxl = (lane & 15) * 4;       // px word within row
#pragma unroll
  for (int i = 0; i < 48; ++i) {
    const int r = i * 4 + rl;            // 0..191 = n*64 + c
    const int n = r >> 6, c = r & 63;
    const float* g = ctx + ((((size_t)b * NCTX + n) * CH + c) * FS + hrow) * FS + x0 + pxl;
    __builtin_amdgcn_global_load_lds((glob_u32*)g, (lds_u32*)(slot + i * 256), 16, 0, 0);
  }
}

// ---------------------------------------------------------------------------
// fused_kernel v3: block=(b,y), 512 thr, 1 block/CU (149.5 KB LDS).
// Phase A = v1 exactly (results spill to LDS overlay). Phase B = 4 units
// (u,x2), ctx double-buffered in LDS via global_load_lds; ALL barriers are
// raw s_barrier + lgkmcnt(0) so staging loads stay in flight across them;
// wave 0 is producer with counted vmcnt gating (never vmcnt(0) mid-loop).
// ---------------------------------------------------------------------------
__global__ __launch_bounds__(512) void fused_kernel(
    const float* __restrict__ m, const float* __restrict__ Vb,
    const float* __restrict__ bk, const float* __restrict__ ctx,
    float* __restrict__ out, const float* __restrict__ ws) {
  const int b = blockIdx.x >> 6, y = blockIdx.x & 63;
  const int t = threadIdx.x, lane = t & 63;
  const int wave = __builtin_amdgcn_readfirstlane(t >> 6);
  const int am = lane & 31, kh = lane >> 5;

  __shared__ __align__(16) union {
    short HI[3][8][66][2][8];            // 50688 B, phase A staging
    struct {                             // 39168 B, phase B (HI dead)
      float  QT[CH][64];                 // row y queries, with bq
      float  VAL[CH][64];                // row y conv values, with Vb
      float4 wpart[8][3][16];            // [wave][n][quad] logit partials
      float  L3[64];                     // row y self-logits
    } p;
  } U;
  __shared__ __align__(16) float CTXB[2][NCTX][CH][64];   // 98304 B ctx ring
  __shared__ float l3red[2][64];

  // ---- zero x-borders (cols 0 and 65) ----
  if (t < 96) {
    int row = t / 32, kf = (t >> 2) & 7, khh = (t >> 1) & 1, col = (t & 1) * 65;
    s16x8 z;
#pragma unroll
    for (int j = 0; j < 8; ++j) z[j] = 0;
    *(s16x8*)&U.HI[row][kf][col][khh][0] = z;
  }

  // ---- stage hi: 48 wave-tasks (row,kf,kh), 6 per wave; coalesced reads ----
#pragma unroll
  for (int i = 0; i < 6; ++i) {
    const int tk = wave * 6 + i;               // 0..47
    const int row = tk >> 4, kf = (tk >> 1) & 7, khh = tk & 1;
    const int yy = y + row - 1;
    s16x8 hi;
    if (yy >= 0 && yy < HS) {
#pragma unroll
      for (int j = 0; j < 8; ++j) {
        const int f = kf * 16 + khh * 8 + j;
        hi[j] = (short)bf16_rne(m[((b * FD + f) * HS + yy) * HS + lane]);
      }
    } else {
#pragma unroll
      for (int j = 0; j < 8; ++j) hi[j] = 0;
    }
    *(s16x8*)&U.HI[row][kf][lane + 1][khh][0] = hi;
  }

  // ---- producer: prefetch unit 0 ctx (overlaps all of phase A) ----
  __builtin_amdgcn_sched_barrier(0);
  if (wave == 0) issue_unit(ctx, &CTXB[0][0][0][0], b, 2 * y, 0, lane);
  rbar();                                      // B1: HI staged

  const int ct = (wave >> 1) & 1;
  const int xh = wave & 1;
  const int x0 = xh * 32, ch0 = ct * 32;

  f32x16 acc, q1, q2, k1, k2;
  float l3part = 0.f;

  if (wave < 4) {
    // ---- conv: tile (ct,xh), all 72 K-chunks, A-hi x B-hi ----
    const unsigned short* avh = (const unsigned short*)(ws + WS_AVH);
#pragma unroll
    for (int i = 0; i < 16; ++i) acc[i] = 0.f;
#pragma unroll 8
    for (int q = 0; q < 72; ++q) {
      const int tap = q >> 3, kf = q & 7;
      const s16x8 ah = *(const s16x8*)(avh + ((ct * 72 + q) * 64 + lane) * 8);
      const s16x8 bh = *(const s16x8*)&U.HI[tap / 3][kf][x0 + am + tap % 3][kh][0];
      acc = __builtin_amdgcn_mfma_f32_32x32x16_bf16(ah, bh, acc, 0, 0, 0);
    }
  } else {
    // ---- qt + keys: K=128, 3-MFMA hi/lo split each ----
    const unsigned short* aqh = (const unsigned short*)(ws + WS_AQH);
    const unsigned short* aql = (const unsigned short*)(ws + WS_AQL);
    const unsigned short* akh = (const unsigned short*)(ws + WS_AKH);
    const unsigned short* akl = (const unsigned short*)(ws + WS_AKL);
#pragma unroll
    for (int i = 0; i < 16; ++i) { q1[i] = 0.f; q2[i] = 0.f; k1[i] = 0.f; k2[i] = 0.f; }
#pragma unroll
    for (int q = 0; q < 8; ++q) {
      const s16x8 bh = *(const s16x8*)&U.HI[1][q][x0 + am + 1][kh][0];
      s16x8 bl;
#pragma unroll
      for (int j = 0; j < 8; ++j) {
        const float mv = m[((b * FD + q * 16 + kh * 8 + j) * HS + y) * HS + x0 + am];
        const float hf = __uint_as_float(((unsigned)(unsigned short)bh[j]) << 16);
        bl[j] = (short)bf16_rne(mv - hf);
      }
      const s16x8 ah = *(const s16x8*)(aqh + ((ct * 8 + q) * 64 + lane) * 8);
      const s16x8 al = *(const s16x8*)(aql + ((ct * 8 + q) * 64 + lane) * 8);
      const s16x8 kah = *(const s16x8*)(akh + ((ct * 8 + q) * 64 + lane) * 8);
      const s16x8 kal = *(const s16x8*)(akl + ((ct * 8 + q) * 64 + lane) * 8);
      q1 = __builtin_amdgcn_mfma_f32_32x32x16_bf16(ah, bh, q1, 0, 0, 0);
      q1 = __builtin_amdgcn_mfma_f32_32x32x16_bf16(al, bh, q1, 0, 0, 0);
      q2 = __builtin_amdgcn_mfma_f32_32x32x16_bf16(ah, bl, q2, 0, 0, 0);
      k1 = __builtin_amdgcn_mfma_f32_32x32x16_bf16(kah, bh, k1, 0, 0, 0);
      k1 = __builtin_amdgcn_mfma_f32_32x32x16_bf16(kal, bh, k1, 0, 0, 0);
      k2 = __builtin_amdgcn_mfma_f32_32x32x16_bf16(kah, bl, k2, 0, 0, 0);
    }
  }
  rbar();                                      // B2: HI reads done, overlay free

  // ---- spill accumulators to LDS overlay ----
  if (wave < 4) {
#pragma unroll
    for (int r = 0; r < 16; ++r) {
      const int c = ch0 + (r & 3) + 8 * (r >> 2) + 4 * kh;
      U.p.VAL[c][x0 + am] = acc[r] + Vb[c];
    }
  } else {
#pragma unroll
    for (int r = 0; r < 16; ++r) {
      const int c = ch0 + (r & 3) + 8 * (r >> 2) + 4 * kh;
      const float qvv = q1[r] + q2[r] + ws[WS_BQ + c];
      const float kvv = k1[r] + k2[r] + bk[c];
      U.p.QT[c][x0 + am] = qvv;
      l3part = fmaf(qvv, kvv, l3part);
    }
    if (ct == 1) l3red[xh][lane] = l3part;     // waves 6,7
  }
  rbar();                                      // B3: QT/VAL/l3red ready

  // ---- l3 finish: waves 4,5 ----
  if (wave == 4 || wave == 5) {
    float s = l3part + l3red[xh][lane];
    s += __shfl_xor(s, 32, 64);
    if (kh == 0) U.p.L3[x0 + am] = s;
  }

  // ---- B4: phase-B entry; producer ensures unit 0 landed ----
  if (wave == 0) asm volatile("s_waitcnt vmcnt(0)" ::: "memory");
  rbar();

  // =======================================================================
  // Phase B: 4 units (u = k>>1 row, x2 = k&1 half), double-buffered ctx.
  // 512 threads on one 64px x 64ch unit: quad = px group, cg = t>>4 (2 ch).
  // =======================================================================
  const int quad = lane & 15;
  const int cg   = t >> 4;                     // 0..31
  const int c0   = 2 * cg;
  const int cs = FS * FS;

#pragma unroll 1
  for (int k = 0; k < 4; ++k) {
    if (wave == 0 && k < 3) {                  // issue next unit (other slot)
      const int kn = k + 1;
      issue_unit(ctx, &CTXB[kn & 1][0][0][0], b, 2 * y + (kn >> 1), 64 * (kn & 1), lane);
    }
    const float* CB = &CTXB[k & 1][0][0][0];
    const int x2 = k & 1, u = k >> 1;
    const int hrow = 2 * y + u;
    const int x = 64 * x2 + quad * 4;
    const int hx = 32 * x2 + quad * 2;

    float4 cv[3][2];
    float2 qv[2], vv[2];
#pragma unroll
    for (int j = 0; j < 2; ++j) {
      qv[j] = *(const float2*)&U.p.QT[c0 + j][hx];
      vv[j] = *(const float2*)&U.p.VAL[c0 + j][hx];
#pragma unroll
      for (int n = 0; n < 3; ++n)
        cv[n][j] = *(const float4*)(CB + ((n * CH + c0 + j) * 64 + quad * 4));
    }

    float4 pl[3];
#pragma unroll
    for (int n = 0; n < 3; ++n) {
      pl[n].x = fmaf(cv[n][1].x, qv[1].x, cv[n][0].x * qv[0].x);
      pl[n].y = fmaf(cv[n][1].y, qv[1].x, cv[n][0].y * qv[0].x);
      pl[n].z = fmaf(cv[n][1].z, qv[1].y, cv[n][0].z * qv[0].y);
      pl[n].w = fmaf(cv[n][1].w, qv[1].y, cv[n][0].w * qv[0].y);
      // reduce over 4 cparts in-wave (lanes ^16, ^32)
      pl[n].x += __shfl_xor(pl[n].x, 16, 64);
      pl[n].y += __shfl_xor(pl[n].y, 16, 64);
      pl[n].z += __shfl_xor(pl[n].z, 16, 64);
      pl[n].w += __shfl_xor(pl[n].w, 16, 64);
      pl[n].x += __shfl_xor(pl[n].x, 32, 64);
      pl[n].y += __shfl_xor(pl[n].y, 32, 64);
      pl[n].z += __shfl_xor(pl[n].z, 32, 64);
      pl[n].w += __shfl_xor(pl[n].w, 32, 64);
    }
    if ((lane >> 4) == 0) {
#pragma unroll
      for (int n = 0; n < 3; ++n) U.p.wpart[wave][n][quad] = pl[n];
    }
    rbar();                                    // wpart ready (loads in flight!)

    float4 L[3];
#pragma unroll
    for (int n = 0; n < 3; ++n) {
      float4 s = U.p.wpart[0][n][quad];
#pragma unroll
      for (int w = 1; w < 8; ++w) {
        const float4 p = U.p.wpart[w][n][quad];
        s.x += p.x; s.y += p.y; s.z += p.z; s.w += p.w;
      }
      L[n] = s;
    }
    const float l3a = U.p.L3[hx], l3b = U.p.L3[hx + 1];

    float A0[4], A1[4], A2[4], A3[4];
    const float* L0p = (const float*)&L[0];
    const float* L1p = (const float*)&L[1];
    const float* L2p = (const float*)&L[2];
#pragma unroll
    for (int kk = 0; kk < 4; ++kk) {
      float L0 = L0p[kk], L1 = L1p[kk], L2 = L2p[kk];
      float L3v = (kk < 2) ? l3a : l3b;
      float mx = fmaxf(fmaxf(L0, L1), fmaxf(L2, L3v));
      float e0 = __expf(L0 - mx), e1 = __expf(L1 - mx);
      float e2 = __expf(L2 - mx), e3 = __expf(L3v - mx);
      float inv = 1.f / (e0 + e1 + e2 + e3);
      A0[kk] = e0 * inv; A1[kk] = e1 * inv; A2[kk] = e2 * inv; A3[kk] = e3 * inv;
    }

    float* op = out + (size_t)(b * CH) * cs + (size_t)hrow * FS + x;
#pragma unroll
    for (int j = 0; j < 2; ++j) {
      const int c = c0 + j;
      float4 o;
      o.x = fmaf(A0[0], cv[0][j].x, fmaf(A1[0], cv[1][j].x, fmaf(A2[0], cv[2][j].x, A3[0] * vv[j].x)));
      o.y = fmaf(A0[1], cv[0][j].y, fmaf(A1[1], cv[1][j].y, fmaf(A2[1], cv[2][j].y, A3[1] * vv[j].x)));
      o.z = fmaf(A0[2], cv[0][j].z, fmaf(A1[2], cv[1][j].z, fmaf(A2[2], cv[2][j].z, A3[2] * vv[j].y)));
      o.w = fmaf(A0[3], cv[0][j].w, fmaf(A1[3], cv[1][j].w, fmaf(A2[3], cv[2][j].w, A3[3] * vv[j].y)));
      *(float4*)(op + c * cs) = o;
    }

    if (k < 3) {
      // producer: all but my 2 newest (own stores) done => next unit landed
      if (wave == 0) asm volatile("s_waitcnt vmcnt(2)" ::: "memory");
      rbar();                                  // release next unit
    }
  }
}

// ---------------------------------------------------------------------------
extern "C" void kernel_launch(void* const* d_in, const int* in_sizes, int n_in,
                              void* d_out, int out_size, void* d_ws, size_t ws_size,
                              hipStream_t stream) {
  const float* ctx = (const float*)d_in[0];
  const float* ms  = (const float*)d_in[1];
  const float* Wc  = (const float*)d_in[2];
  // d_in[3] = bc : cancels in softmax
  const float* Wf  = (const float*)d_in[4];
  const float* bf  = (const float*)d_in[5];
  const float* Wk  = (const float*)d_in[6];
  const float* bk  = (const float*)d_in[7];
  const float* Vw  = (const float*)d_in[8];
  const float* Vb  = (const float*)d_in[9];
  float* ws  = (float*)d_ws;
  float* out = (float*)d_out;

  afrag_prep<<<45, 256, 0, stream>>>(Wc, Wf, bf, Wk, Vw, ws);
  fused_kernel<<<NB * HS, 512, 0, stream>>>(ms, Vb, bk, ctx, out, ws);
}